// Round 6
// baseline (508.700 us; speedup 1.0000x reference)
//
#include <hip/hip_runtime.h>
#include <hip/hip_bf16.h>

// Problem constants (fixed by setup_inputs):
//   B=1, T=16384 -> S=16384, C=1280, H=16, D=80, 3C=3840, block=16, nb=1024
// Inputs FP32, output FP32. Workspace budget 222,822,400 B.
#define S_TOK   16384
#define C_DIM   1280
#define C3_DIM  3840
#define H_DIM   16
#define D_DIM   80
#define BLK     16
#define PLANE_ELEMS ((size_t)S_TOK * C_DIM)   // one of Q/K/V planes, elements

using u16x8  = __attribute__((ext_vector_type(8))) unsigned short;
using u16x4  = __attribute__((ext_vector_type(4))) unsigned short;
using bf16x8 = __attribute__((ext_vector_type(8))) __bf16;
using f32x4  = __attribute__((ext_vector_type(4))) float;

__device__ __forceinline__ unsigned short f2bf(float f) {
    return __bfloat16_as_ushort(__float2bfloat16(f));
}
__device__ __forceinline__ float bf2f(unsigned short u) {
    unsigned int x = (unsigned int)u << 16;
    return __builtin_bit_cast(float, x);
}
__device__ __forceinline__ void gload_lds16(const unsigned short* g, unsigned short* l) {
    __builtin_amdgcn_global_load_lds(
        (const __attribute__((address_space(1))) void*)g,
        (__attribute__((address_space(3))) void*)l, 16, 0, 0);
}
// Swizzled LDS fragment read: logical (row, byte-col cb) of a [*][64]-bf16
// tile stored with byte ^= ((row&7)<<4).  16 lanes (consecutive rows, same
// cb) land on 8 distinct 16-B slots = 2-way aliasing = free (verified 0
// conflicts R1-R5).
__device__ __forceinline__ bf16x8 lds_read_swz(const unsigned short* buf,
                                               int off, int xr, int cb) {
    return *(const bf16x8*)((const char*)buf + off + (cb ^ xr));
}

// ---------------------------------------------------------------------------
// One-shot weight prep: fp32 W[K][N] -> bf16 W^T[N][K], LDS-tiled.
// ---------------------------------------------------------------------------
__global__ __launch_bounds__(256) void transpose_cvt(
    const float* __restrict__ W, unsigned short* __restrict__ WT, int K, int N)
{
    __shared__ float tile[32][33];
    const int n0 = blockIdx.x * 32, k0 = blockIdx.y * 32;
    const int tx = threadIdx.x & 31, ty = threadIdx.x >> 5;   // 32x8
#pragma unroll
    for (int i = ty; i < 32; i += 8)
        tile[i][tx] = W[(size_t)(k0 + i) * N + n0 + tx];
    __syncthreads();
#pragma unroll
    for (int i = ty; i < 32; i += 8)
        WT[(size_t)(n0 + i) * K + k0 + tx] = f2bf(tile[tx][i]);
}

// ---------------------------------------------------------------------------
// Prepass: xg[s][:] = bf16(x[wi[s]][:]).  (enables global_load_lds in GEMM1)
// ---------------------------------------------------------------------------
__global__ __launch_bounds__(256) void gather_cvt(
    const float* __restrict__ x, const int* __restrict__ wi,
    unsigned short* __restrict__ xg)
{
    int idx = blockIdx.x * 256 + threadIdx.x;   // over S*160 (exact)
    int s  = idx / 160;
    int c8 = (idx - s * 160) * 8;
    const float* src = x + (size_t)wi[s] * C_DIM + c8;
    f32x4 v0 = *(const f32x4*)src;
    f32x4 v1 = *(const f32x4*)(src + 4);
    u16x8 o;
    o[0]=f2bf(v0[0]); o[1]=f2bf(v0[1]); o[2]=f2bf(v0[2]); o[3]=f2bf(v0[3]);
    o[4]=f2bf(v1[0]); o[5]=f2bf(v1[1]); o[6]=f2bf(v1[2]); o[7]=f2bf(v1[3]);
    *(u16x8*)&xg[(size_t)s * C_DIM + c8] = o;
}

// ---------------------------------------------------------------------------
// Inverse permutation: inv[wi[s]] = s.
// ---------------------------------------------------------------------------
__global__ __launch_bounds__(256) void inv_perm(
    const int* __restrict__ wi, int* __restrict__ inv)
{
    int s = blockIdx.x * 256 + threadIdx.x;
    inv[wi[s]] = s;
}

// ---------------------------------------------------------------------------
// 256x256 8-wave bf16 MFMA GEMM with counted-vmcnt software pipeline (T3+T4)
// + setprio MFMA clusters (T5).  Replaces the m97-style 128^2 kernel (fixed
// at 862 TF / 39% MfmaUtil R1-R5 = its documented structural ceiling).
//
// Geometry: BK=64, 8 waves (2M x 4N), per-wave C = 128x64 (acc[8][4]).
// LDS: 2 full-tile double buffers, A+B = 4 x 32 KB = 128 KB -> 1 WG/CU.
// Tile t lives in buf[t&1].
//
// Schedule per K-tile t (raw s_barrier only -- NO __syncthreads, so no
// vmcnt(0) drain):
//   P1: ds_read ks0 (12 x b128)            ; 32 MFMA  [setprio]
//   P2: ds_read ks1 (12 x b128)            ; 16 MFMA (mt0-3)
//       lgkmcnt(0); barrier                <- buf[cur] fully consumed
//   P3: STAGE tile t+2 -> buf[cur] (8 x global_load_lds, 16 B)
//       16 MFMA (mt4-7)
//       vmcnt(8); barrier                  <- tile t+1 landed; t+2's 8 loads
//                                             stay IN FLIGHT across barrier
// Hazards: write-after-read by P2's lgkmcnt(0)+barrier; read-after-write by
// counted vmcnt(8)+barrier (per-wave counts: every wave issues exactly 8
// loads/tile); compiler reordering fenced by sched_barrier(0) (rule #18).
//
//   OUTMODE 0: fp32 [M][N] contiguous
//   OUTMODE 2: bf16 planes [which][h][s][d]
//   GATHER   : A-row gather via row_map (read-side un-permute)
// ---------------------------------------------------------------------------
#define BK2 64

template<int OUTMODE, bool GATHER>
__global__ __launch_bounds__(512, 2) void gemm256(
    const unsigned short* __restrict__ A,   // [M][K] bf16
    const unsigned short* __restrict__ BT,  // [N][K] bf16
    void* __restrict__ Cp,
    const int* __restrict__ row_map,
    int N, int K)
{
    __shared__ __align__(16) unsigned short AsB[2 * 16384];
    __shared__ __align__(16) unsigned short BsB[2 * 16384];

    const int m0   = blockIdx.x * 256;
    const int n0   = blockIdx.y * 256;
    const int tid  = threadIdx.x;           // 0..511
    const int lane = tid & 63;
    const int wv   = tid >> 6;              // 0..7
    const int wm   = (wv >> 2) * 128;       // A half
    const int wn   = (wv & 3) * 64;         // B quarter
    const int lrow = lane & 15;
    const int quad = lane >> 4;

    // Staging sources: 4 A-chunks + 4 B-chunks of 16 B per thread per tile.
    // chunk gch -> row gch>>3, inverse-swizzled col ((gch&7)^(row&7))*8.
    const unsigned short* pa[4];
    const unsigned short* pb[4];
#pragma unroll
    for (int i = 0; i < 4; i++) {
        int gch = i * 512 + tid;
        int r   = gch >> 3;                            // 0..255
        int c   = ((gch & 7) ^ (r & 7)) << 3;
        int ga  = GATHER ? row_map[m0 + r] : (m0 + r); // hoisted, K-invariant
        pa[i] = A  + (size_t)ga * K + c;
        pb[i] = BT + (size_t)(n0 + r) * K + c;
    }

    // ds_read offsets (byte base + XOR key per fragment row)
    int aoff[8], axr[8], boff[4], bxr[4];
#pragma unroll
    for (int mt = 0; mt < 8; mt++) {
        int r = wm + mt * 16 + lrow;
        aoff[mt] = r << 7;  axr[mt] = (r & 7) << 4;
    }
#pragma unroll
    for (int nt = 0; nt < 4; nt++) {
        int r = wn + nt * 16 + lrow;
        boff[nt] = r << 7;  bxr[nt] = (r & 7) << 4;
    }

    f32x4 acc[8][4];
#pragma unroll
    for (int i = 0; i < 8; i++)
#pragma unroll
        for (int j = 0; j < 4; j++)
            acc[i][j] = (f32x4){0.f, 0.f, 0.f, 0.f};

    const int NT = K >> 6;                  // 20 here

    auto stage = [&](int bsel, int koff) {
#pragma unroll
        for (int i = 0; i < 4; i++)         // dest: wave-uniform base +lane*16
            gload_lds16(pa[i] + koff, AsB + bsel * 16384 + i * 4096 + wv * 512);
#pragma unroll
        for (int i = 0; i < 4; i++)
            gload_lds16(pb[i] + koff, BsB + bsel * 16384 + i * 4096 + wv * 512);
    };

    // prologue: tiles 0 and 1 in flight; wait only for tile 0 (vmcnt(8)).
    stage(0, 0);
    stage(1, BK2);
    asm volatile("s_waitcnt vmcnt(8)" ::: "memory");
    __builtin_amdgcn_sched_barrier(0);
    __builtin_amdgcn_s_barrier();
    __builtin_amdgcn_sched_barrier(0);

    int cur = 0;
    for (int t = 0; t < NT; ++t) {
        const unsigned short* Ac = AsB + cur * 16384;
        const unsigned short* Bc = BsB + cur * 16384;
        const int cb0 = quad << 4;          // ks0 byte col
        const int cb1 = 64 + (quad << 4);   // ks1 byte col

        // ---- P1: ks0 ----
        bf16x8 a0[8], b0[4];
#pragma unroll
        for (int mt = 0; mt < 8; mt++) a0[mt] = lds_read_swz(Ac, aoff[mt], axr[mt], cb0);
#pragma unroll
        for (int nt = 0; nt < 4; nt++) b0[nt] = lds_read_swz(Bc, boff[nt], bxr[nt], cb0);
        __builtin_amdgcn_s_setprio(1);
#pragma unroll
        for (int mt = 0; mt < 8; mt++)
#pragma unroll
            for (int nt = 0; nt < 4; nt++)
                acc[mt][nt] = __builtin_amdgcn_mfma_f32_16x16x32_bf16(
                    a0[mt], b0[nt], acc[mt][nt], 0, 0, 0);
        __builtin_amdgcn_s_setprio(0);

        // ---- P2: ks1 reads + first half of its MFMAs ----
        bf16x8 a1[8], b1[4];
#pragma unroll
        for (int mt = 0; mt < 8; mt++) a1[mt] = lds_read_swz(Ac, aoff[mt], axr[mt], cb1);
#pragma unroll
        for (int nt = 0; nt < 4; nt++) b1[nt] = lds_read_swz(Bc, boff[nt], bxr[nt], cb1);
        __builtin_amdgcn_s_setprio(1);
#pragma unroll
        for (int mt = 0; mt < 4; mt++)
#pragma unroll
            for (int nt = 0; nt < 4; nt++)
                acc[mt][nt] = __builtin_amdgcn_mfma_f32_16x16x32_bf16(
                    a1[mt], b1[nt], acc[mt][nt], 0, 0, 0);
        __builtin_amdgcn_s_setprio(0);
        asm volatile("s_waitcnt lgkmcnt(0)" ::: "memory");  // all buf[cur] reads done
        __builtin_amdgcn_sched_barrier(0);
        __builtin_amdgcn_s_barrier();
        __builtin_amdgcn_sched_barrier(0);

        // ---- P3: re-stage buf[cur] with tile t+2; finish ks1 ----
        if (t + 2 < NT) stage(cur, (t + 2) * BK2);
        __builtin_amdgcn_s_setprio(1);
#pragma unroll
        for (int mt = 4; mt < 8; mt++)
#pragma unroll
            for (int nt = 0; nt < 4; nt++)
                acc[mt][nt] = __builtin_amdgcn_mfma_f32_16x16x32_bf16(
                    a1[mt], b1[nt], acc[mt][nt], 0, 0, 0);
        __builtin_amdgcn_s_setprio(0);
        if (t + 2 < NT) {
            asm volatile("s_waitcnt vmcnt(8)" ::: "memory"); // t+1 landed; t+2 floats
        } else if (t + 1 < NT) {
            asm volatile("s_waitcnt vmcnt(0)" ::: "memory"); // final drain
        }
        __builtin_amdgcn_sched_barrier(0);
        __builtin_amdgcn_s_barrier();
        __builtin_amdgcn_sched_barrier(0);
        cur ^= 1;
    }

    // epilogue: D row = quad*4 + r, col = lane&15 (HW-verified C/D layout)
#pragma unroll
    for (int nt = 0; nt < 4; nt++) {
        const int cb = n0 + wn + nt * 16;              // uniform per nt
        unsigned short* pp = nullptr;
        if (OUTMODE == 2) {
            int which = cb / C_DIM;
            int hc    = cb - which * C_DIM;
            int h     = hc / D_DIM;
            int d0    = hc - h * D_DIM;
            pp = (unsigned short*)Cp + (size_t)which * PLANE_ELEMS
               + (size_t)h * S_TOK * D_DIM + d0 + lrow;
        }
#pragma unroll
        for (int mt = 0; mt < 8; mt++)
#pragma unroll
            for (int r = 0; r < 4; r++) {
                int row = m0 + wm + mt * 16 + quad * 4 + r;
                if (OUTMODE == 0)
                    ((float*)Cp)[(size_t)row * N + cb + lrow] = acc[mt][nt][r];
                else
                    pp[(size_t)row * D_DIM] = f2bf(acc[mt][nt][r]);
            }
    }
}

// ---------------------------------------------------------------------------
// Fused RoPE + block attention v2 (unchanged from R4/R5 — ~50 us).
// ---------------------------------------------------------------------------
__global__ __launch_bounds__(256) void attn_v2(
    const unsigned short* __restrict__ planes,  // [3][H][S][D] bf16
    const float* __restrict__ cosp,
    const float* __restrict__ sinp,
    const int* __restrict__ wi,
    unsigned short* __restrict__ yw)            // [S][1280] bf16, WINDOWED
{
    __shared__ __align__(16) unsigned short Q_lds[4][16][88];
    __shared__ __align__(16) unsigned short K_lds[4][16][88];
    __shared__ __align__(16) unsigned short V_lds[4][1536];

    const int wave = threadIdx.x >> 6;
    const int lane = threadIdx.x & 63;
    const int b    = blockIdx.y;
    const int h    = blockIdx.x * 4 + wave;
    const int j16  = lane & 15;
    const int quad = lane >> 4;

    const unsigned short* Vsrc = planes + 2 * PLANE_ELEMS
        + ((size_t)h * S_TOK + b * BLK) * D_DIM;
    unsigned short* Vsl = &V_lds[wave][0];
#pragma unroll
    for (int c = 0; c < 3; c++)
        gload_lds16(Vsrc + c * 512 + lane * 8, Vsl + c * 512);

    const unsigned short* Qbase = planes + ((size_t)h * S_TOK + b * BLK) * D_DIM;
#pragma unroll
    for (int c = 0; c < 3; c++) {
        int ch = c * 64 + lane;
        if (ch < 160) {
            int r  = ch / 10;
            int d8 = (ch - r * 10) * 8;
            int crow = wi[b * BLK + r];
            const unsigned short* Qp = Qbase + (size_t)r * D_DIM + d8;
            u16x8 qv = *(const u16x8*)Qp;
            u16x8 kv = *(const u16x8*)(Qp + PLANE_ELEMS);
            const float* cp = cosp + (size_t)crow * D_DIM + d8;
            const float* sp = sinp + (size_t)crow * D_DIM + d8;
            f32x4 c0 = *(const f32x4*)cp, c1 = *(const f32x4*)(cp + 4);
            f32x4 s0 = *(const f32x4*)sp, s1 = *(const f32x4*)(sp + 4);
            u16x8 qo, ko;
#pragma unroll
            for (int j = 0; j < 8; j++) {
                float cw = (j < 4) ? c0[j] : c1[j - 4];
                float sw = (j < 4) ? s0[j] : s1[j - 4];
                float q = bf2f(qv[j]), k = bf2f(kv[j]);
                qo[j] = f2bf(q * cw + k * sw);
                ko[j] = f2bf(k * cw - q * sw);
            }
            *(u16x8*)&Q_lds[wave][r][d8] = qo;
            *(u16x8*)&K_lds[wave][r][d8] = ko;
        }
    }

    asm volatile("s_waitcnt vmcnt(0)" ::: "memory");
    __builtin_amdgcn_sched_barrier(0);

    const u16x8 zz = {0, 0, 0, 0, 0, 0, 0, 0};
    bf16x8 qf[3], kf[3];
#pragma unroll
    for (int s = 0; s < 3; s++) {
        int dcol = 32 * s + quad * 8;
        bool pad = (dcol >= D_DIM);
        int dc = pad ? 0 : dcol;
        u16x8 qv = *(const u16x8*)&Q_lds[wave][j16][dc];
        u16x8 kv = *(const u16x8*)&K_lds[wave][j16][dc];
        if (pad) { qv = zz; kv = zz; }
        qf[s] = __builtin_bit_cast(bf16x8, qv);
        kf[s] = __builtin_bit_cast(bf16x8, kv);
    }

    f32x4 sacc = (f32x4){0.f, 0.f, 0.f, 0.f};
#pragma unroll
    for (int s = 0; s < 3; s++)
        sacc = __builtin_amdgcn_mfma_f32_16x16x32_bf16(kf[s], qf[s], sacc, 0, 0, 0);

    const float scale = 0.11180339887498948f;   // 1/sqrt(80)
    float sc[4];
#pragma unroll
    for (int r = 0; r < 4; r++) sc[r] = sacc[r] * scale;
    float m = fmaxf(fmaxf(sc[0], sc[1]), fmaxf(sc[2], sc[3]));
    m = fmaxf(m, __shfl_xor(m, 16));
    m = fmaxf(m, __shfl_xor(m, 32));
    float e[4], sum = 0.f;
#pragma unroll
    for (int r = 0; r < 4; r++) { e[r] = __expf(sc[r] - m); sum += e[r]; }
    sum += __shfl_xor(sum, 16);
    sum += __shfl_xor(sum, 32);
    float inv = 1.f / sum;

    int sl = quad * 32 + j16;
    float pv0[4], pv1[4];
#pragma unroll
    for (int r = 0; r < 4; r++) pv0[r] = __shfl(e[r], sl & 63);
#pragma unroll
    for (int r = 0; r < 4; r++) pv1[r] = __shfl(e[r], (sl + 16) & 63);
    u16x8 pf;
#pragma unroll
    for (int r = 0; r < 4; r++) {
        pf[r]     = (quad < 2) ? f2bf(pv0[r]) : (unsigned short)0;
        pf[r + 4] = (quad < 2) ? f2bf(pv1[r]) : (unsigned short)0;
    }
    bf16x8 pfrag = __builtin_bit_cast(bf16x8, pf);

    u16x8 vf[5];
#pragma unroll
    for (int t = 0; t < 5; t++) {
#pragma unroll
        for (int e8 = 0; e8 < 8; e8++) {
            int kks = quad * 8 + e8;
            if (kks >= BLK) kks = e8;
            vf[t][e8] = Vsl[kks * D_DIM + t * 16 + j16];
        }
    }

    unsigned short* yrow = yw + (size_t)(b * BLK + j16) * C_DIM
                         + h * D_DIM + quad * 4;
#pragma unroll
    for (int t = 0; t < 5; t++) {
        f32x4 o = __builtin_amdgcn_mfma_f32_16x16x32_bf16(
            __builtin_bit_cast(bf16x8, vf[t]), pfrag,
            (f32x4){0.f, 0.f, 0.f, 0.f}, 0, 0, 0);
        u16x4 ov;
#pragma unroll
        for (int r = 0; r < 4; r++) ov[r] = f2bf(o[r] * inv);
        *(u16x4*)(yrow + t * 16) = ov;
    }
}

extern "C" void kernel_launch(void* const* d_in, const int* in_sizes, int n_in,
                              void* d_out, int out_size, void* d_ws, size_t ws_size,
                              hipStream_t stream)
{
    const float* x     = (const float*)d_in[0];
    const float* cosp  = (const float*)d_in[1];
    const float* sinp  = (const float*)d_in[2];
    const float* Wqkv  = (const float*)d_in[3];
    const float* Wproj = (const float*)d_in[4];
    const int*   wi    = (const int*)d_in[5];

    // workspace layout (bytes):
    //   qkv planes @ 0        : S*3840*2    = 125,829,120  ([3][H][S][D])
    //   yw     @ 125829120    : S*1280*2    =  41,943,040  (windowed order)
    //   wqkvT  @ 167772160    : 3840*1280*2 =   9,830,400   (bf16 [N][K])
    //   wprojT @ 177602560    : 1280*1280*2 =   3,276,800   (bf16 [N][K])
    //   xg     @ 180879360    : S*1280*2    =  41,943,040   (bf16 gathered x)
    //   inv    @ 180879360    : S*4 — ALIASES xg; written after GEMM1.
    char* ws = (char*)d_ws;
    unsigned short* planes = (unsigned short*)ws;
    unsigned short* yw     = (unsigned short*)(ws + 125829120ull);
    unsigned short* wqkvT  = (unsigned short*)(ws + 167772160ull);
    unsigned short* wprojT = (unsigned short*)(ws + 177602560ull);
    unsigned short* xg     = (unsigned short*)(ws + 180879360ull);
    int*            inv    = (int*)(ws + 180879360ull);

    // 0) weight prep: fp32 [K][N] -> bf16 [N][K]
    transpose_cvt<<<dim3(C3_DIM / 32, C_DIM / 32), 256, 0, stream>>>(
        Wqkv, wqkvT, C_DIM, C3_DIM);
    transpose_cvt<<<dim3(C_DIM / 32, C_DIM / 32), 256, 0, stream>>>(
        Wproj, wprojT, C_DIM, C_DIM);

    // 0b) gather + cvt prepass: xg[s] = bf16(x[wi[s]])
    gather_cvt<<<S_TOK * 160 / 256, 256, 0, stream>>>(x, wi, xg);

    // 1) qkv = xg @ W_qkv, written as [3][H][S][D] planes (rope fused in attn)
    gemm256<2, false><<<dim3(S_TOK / 256, C3_DIM / 256), 512, 0, stream>>>(
        xg, wqkvT, planes, nullptr, C3_DIM, C_DIM);

    // 1b) inverse permutation (xg dead; reuse its space)
    inv_perm<<<S_TOK / 256, 256, 0, stream>>>(wi, inv);

    // 2) fused rope + block attention; output WINDOWED (contiguous)
    attn_v2<<<dim3(H_DIM / 4, S_TOK / BLK), 256, 0, stream>>>(
        planes, cosp, sinp, wi, yw);

    // 3) out[r'] = yw[inv[r']] @ W_proj -> fp32 d_out (read-side un-permute)
    gemm256<0, true><<<dim3(S_TOK / 256, C_DIM / 256), 512, 0, stream>>>(
        yw, wprojT, d_out, inv, C_DIM, C_DIM);
}

// Round 7
// 494.874 us; speedup vs baseline: 1.0279x; 1.0279x over previous
//
#include <hip/hip_runtime.h>
#include <hip/hip_bf16.h>

// Problem constants (fixed by setup_inputs):
//   B=1, T=16384 -> S=16384, C=1280, H=16, D=80, 3C=3840, block=16, nb=1024
// Inputs FP32, output FP32. Workspace budget 222,822,400 B.
#define S_TOK   16384
#define C_DIM   1280
#define C3_DIM  3840
#define H_DIM   16
#define D_DIM   80
#define BLK     16
#define PLANE_ELEMS ((size_t)S_TOK * C_DIM)   // one of Q/K/V planes, elements

using u16x8  = __attribute__((ext_vector_type(8))) unsigned short;
using u16x4  = __attribute__((ext_vector_type(4))) unsigned short;
using bf16x8 = __attribute__((ext_vector_type(8))) __bf16;
using f32x4  = __attribute__((ext_vector_type(4))) float;

__device__ __forceinline__ unsigned short f2bf(float f) {
    return __bfloat16_as_ushort(__float2bfloat16(f));
}
__device__ __forceinline__ float bf2f(unsigned short u) {
    unsigned int x = (unsigned int)u << 16;
    return __builtin_bit_cast(float, x);
}
__device__ __forceinline__ void gload_lds16(const unsigned short* g, unsigned short* l) {
    __builtin_amdgcn_global_load_lds(
        (const __attribute__((address_space(1))) void*)g,
        (__attribute__((address_space(3))) void*)l, 16, 0, 0);
}
// Swizzled LDS fragment read: logical (row, byte-col cb) of a [*][64]-bf16
// tile stored with byte ^= ((row&7)<<4).  Verified 0 conflicts R1-R6.
__device__ __forceinline__ bf16x8 lds_read_swz(const unsigned short* buf,
                                               int off, int xr, int cb) {
    return *(const bf16x8*)((const char*)buf + off + (cb ^ xr));
}

// ---------------------------------------------------------------------------
// One-shot weight prep: fp32 W[K][N] -> bf16 W^T[N][K], LDS-tiled.
// ---------------------------------------------------------------------------
__global__ __launch_bounds__(256) void transpose_cvt(
    const float* __restrict__ W, unsigned short* __restrict__ WT, int K, int N)
{
    __shared__ float tile[32][33];
    const int n0 = blockIdx.x * 32, k0 = blockIdx.y * 32;
    const int tx = threadIdx.x & 31, ty = threadIdx.x >> 5;   // 32x8
#pragma unroll
    for (int i = ty; i < 32; i += 8)
        tile[i][tx] = W[(size_t)(k0 + i) * N + n0 + tx];
    __syncthreads();
#pragma unroll
    for (int i = ty; i < 32; i += 8)
        WT[(size_t)(n0 + i) * K + k0 + tx] = f2bf(tile[tx][i]);
}

// ---------------------------------------------------------------------------
// Prepass: xg[s][:] = bf16(x[wi[s]][:]).  (enables global_load_lds in GEMM1)
// ---------------------------------------------------------------------------
__global__ __launch_bounds__(256) void gather_cvt(
    const float* __restrict__ x, const int* __restrict__ wi,
    unsigned short* __restrict__ xg)
{
    int idx = blockIdx.x * 256 + threadIdx.x;   // over S*160 (exact)
    int s  = idx / 160;
    int c8 = (idx - s * 160) * 8;
    const float* src = x + (size_t)wi[s] * C_DIM + c8;
    f32x4 v0 = *(const f32x4*)src;
    f32x4 v1 = *(const f32x4*)(src + 4);
    u16x8 o;
    o[0]=f2bf(v0[0]); o[1]=f2bf(v0[1]); o[2]=f2bf(v0[2]); o[3]=f2bf(v0[3]);
    o[4]=f2bf(v1[0]); o[5]=f2bf(v1[1]); o[6]=f2bf(v1[2]); o[7]=f2bf(v1[3]);
    *(u16x8*)&xg[(size_t)s * C_DIM + c8] = o;
}

// ---------------------------------------------------------------------------
// Inverse permutation: inv[wi[s]] = s.
// ---------------------------------------------------------------------------
__global__ __launch_bounds__(256) void inv_perm(
    const int* __restrict__ wi, int* __restrict__ inv)
{
    int s = blockIdx.x * 256 + threadIdx.x;
    inv[wi[s]] = s;
}

// ---------------------------------------------------------------------------
// 256x256 8-wave bf16 MFMA GEMM, v2: counted-vmcnt pipeline with a SINGLE
// scheduling region per K-tile.
//
// R6 post-mortem: the per-cluster setprio pairs acted as code-motion fences,
// serializing the 24-ds_read LDS stream (96 LDS-clk/wave @ 256 B/clk) against
// the 64-MFMA stream (310 clk/wave) inside the lone WG/CU -> 34% MfmaUtil.
// v2 keeps R6's EXACT sync points (lgkmcnt(0)+barrier before re-stage;
// counted vmcnt(8)+barrier after; raw s_barrier, never a vmcnt(0) drain in
// the steady loop) but wraps the whole {MFMA ks0; reads ks1; MFMA ks1} in one
// setprio region so the compiler can stream ds_reads under MFMAs.
// LDS-BW model: 256^2 cap = 620 MFMA-clk/SIMD vs 768 LDS-clk/CU -> ~81%.
//
// + bijective XCD-chunked blockIdx swizzle (nwg % 8 == 0 for both call sites).
//
//   OUTMODE 0: fp32 [M][N] contiguous
//   OUTMODE 2: bf16 planes [which][h][s][d]
//   GATHER   : A-row gather via row_map
// ---------------------------------------------------------------------------
#define BK2 64

template<int OUTMODE, bool GATHER>
__global__ __launch_bounds__(512, 2) void gemm256(
    const unsigned short* __restrict__ A,   // [M][K] bf16
    const unsigned short* __restrict__ BT,  // [N][K] bf16
    void* __restrict__ Cp,
    const int* __restrict__ row_map,
    int N, int K)
{
    __shared__ __align__(16) unsigned short AsB[2 * 16384];
    __shared__ __align__(16) unsigned short BsB[2 * 16384];

    // XCD-chunked swizzle (bijective: gridDim.x*gridDim.y % 8 == 0 here).
    const int nwg  = gridDim.x * gridDim.y;
    const int wgid = blockIdx.y * gridDim.x + blockIdx.x;
    const int cpx  = nwg >> 3;
    const int swz  = (wgid & 7) * cpx + (wgid >> 3);
    const int m0   = (swz % gridDim.x) * 256;
    const int n0   = (swz / gridDim.x) * 256;

    const int tid  = threadIdx.x;           // 0..511
    const int lane = tid & 63;
    const int wv   = tid >> 6;              // 0..7
    const int wm   = (wv >> 2) * 128;       // A half
    const int wn   = (wv & 3) * 64;         // B quarter
    const int lrow = lane & 15;
    const int quad = lane >> 4;

    // Staging sources: 4 A-chunks + 4 B-chunks of 16 B per thread per tile.
    const unsigned short* pa[4];
    const unsigned short* pb[4];
#pragma unroll
    for (int i = 0; i < 4; i++) {
        int gch = i * 512 + tid;
        int r   = gch >> 3;                            // 0..255
        int c   = ((gch & 7) ^ (r & 7)) << 3;
        int ga  = GATHER ? row_map[m0 + r] : (m0 + r);
        pa[i] = A  + (size_t)ga * K + c;
        pb[i] = BT + (size_t)(n0 + r) * K + c;
    }

    // ds_read offsets (byte base + XOR key per fragment row)
    int aoff[8], axr[8], boff[4], bxr[4];
#pragma unroll
    for (int mt = 0; mt < 8; mt++) {
        int r = wm + mt * 16 + lrow;
        aoff[mt] = r << 7;  axr[mt] = (r & 7) << 4;
    }
#pragma unroll
    for (int nt = 0; nt < 4; nt++) {
        int r = wn + nt * 16 + lrow;
        boff[nt] = r << 7;  bxr[nt] = (r & 7) << 4;
    }

    f32x4 acc[8][4];
#pragma unroll
    for (int i = 0; i < 8; i++)
#pragma unroll
        for (int j = 0; j < 4; j++)
            acc[i][j] = (f32x4){0.f, 0.f, 0.f, 0.f};

    const int NT = K >> 6;                  // 20 here

    auto stage = [&](int bsel, int koff) {
#pragma unroll
        for (int i = 0; i < 4; i++)
            gload_lds16(pa[i] + koff, AsB + bsel * 16384 + i * 4096 + wv * 512);
#pragma unroll
        for (int i = 0; i < 4; i++)
            gload_lds16(pb[i] + koff, BsB + bsel * 16384 + i * 4096 + wv * 512);
    };

    // prologue: tiles 0 and 1 in flight; wait only tile 0 (vmcnt(8)).
    stage(0, 0);
    stage(1, BK2);
    asm volatile("s_waitcnt vmcnt(8)" ::: "memory");
    __builtin_amdgcn_sched_barrier(0);
    __builtin_amdgcn_s_barrier();
    __builtin_amdgcn_sched_barrier(0);

    int cur = 0;
    for (int t = 0; t < NT; ++t) {
        const unsigned short* Ac = AsB + cur * 16384;
        const unsigned short* Bc = BsB + cur * 16384;
        const int cb0 = quad << 4;          // ks0 byte col
        const int cb1 = 64 + (quad << 4);   // ks1 byte col

        // ks0 fragments
        bf16x8 a0[8], b0[4];
#pragma unroll
        for (int mt = 0; mt < 8; mt++) a0[mt] = lds_read_swz(Ac, aoff[mt], axr[mt], cb0);
#pragma unroll
        for (int nt = 0; nt < 4; nt++) b0[nt] = lds_read_swz(Bc, boff[nt], bxr[nt], cb0);

        // Single scheduling region: ks0 MFMAs, ks1 reads, ks1 MFMAs may
        // interleave freely (no internal fences) -> LDS stream hides under
        // the MFMA stream.
        __builtin_amdgcn_s_setprio(1);
#pragma unroll
        for (int mt = 0; mt < 8; mt++)
#pragma unroll
            for (int nt = 0; nt < 4; nt++)
                acc[mt][nt] = __builtin_amdgcn_mfma_f32_16x16x32_bf16(
                    a0[mt], b0[nt], acc[mt][nt], 0, 0, 0);

        bf16x8 a1[8], b1[4];
#pragma unroll
        for (int mt = 0; mt < 8; mt++) a1[mt] = lds_read_swz(Ac, aoff[mt], axr[mt], cb1);
#pragma unroll
        for (int nt = 0; nt < 4; nt++) b1[nt] = lds_read_swz(Bc, boff[nt], bxr[nt], cb1);
#pragma unroll
        for (int mt = 0; mt < 8; mt++)
#pragma unroll
            for (int nt = 0; nt < 4; nt++)
                acc[mt][nt] = __builtin_amdgcn_mfma_f32_16x16x32_bf16(
                    a1[mt], b1[nt], acc[mt][nt], 0, 0, 0);
        __builtin_amdgcn_s_setprio(0);

        // all buf[cur] reads done (mine: lgkmcnt; everyone's: barrier)
        asm volatile("s_waitcnt lgkmcnt(0)" ::: "memory");
        __builtin_amdgcn_sched_barrier(0);
        __builtin_amdgcn_s_barrier();
        __builtin_amdgcn_sched_barrier(0);

        // re-stage buf[cur] with tile t+2; counted wait: t+1 landed, t+2's
        // 8 loads stay in flight across the barrier (never vmcnt(0) here).
        if (t + 2 < NT) {
            stage(cur, (t + 2) * BK2);
            asm volatile("s_waitcnt vmcnt(8)" ::: "memory");
        } else if (t + 1 < NT) {
            asm volatile("s_waitcnt vmcnt(0)" ::: "memory"); // final drain
        }
        __builtin_amdgcn_sched_barrier(0);
        __builtin_amdgcn_s_barrier();
        __builtin_amdgcn_sched_barrier(0);
        cur ^= 1;
    }

    // epilogue: D row = quad*4 + r, col = lane&15 (HW-verified C/D layout)
#pragma unroll
    for (int nt = 0; nt < 4; nt++) {
        const int cb = n0 + wn + nt * 16;              // uniform per nt
        unsigned short* pp = nullptr;
        if (OUTMODE == 2) {
            int which = cb / C_DIM;
            int hc    = cb - which * C_DIM;
            int h     = hc / D_DIM;
            int d0    = hc - h * D_DIM;
            pp = (unsigned short*)Cp + (size_t)which * PLANE_ELEMS
               + (size_t)h * S_TOK * D_DIM + d0 + lrow;
        }
#pragma unroll
        for (int mt = 0; mt < 8; mt++)
#pragma unroll
            for (int r = 0; r < 4; r++) {
                int row = m0 + wm + mt * 16 + quad * 4 + r;
                if (OUTMODE == 0)
                    ((float*)Cp)[(size_t)row * N + cb + lrow] = acc[mt][nt][r];
                else
                    pp[(size_t)row * D_DIM] = f2bf(acc[mt][nt][r]);
            }
    }
}

// ---------------------------------------------------------------------------
// 128x128 4-wave GEMM (R5-proven, 862 TF, 0 conflicts) — used for GEMM2:
// 1280 WGs -> ~3 WG/CU implicit overlap; A-row gather = read-side un-permute.
// ---------------------------------------------------------------------------
#define TM 128
#define TN 128
#define BK 64

template<int OUTMODE, bool GATHER>
__global__ __launch_bounds__(256) void gemm_mfma(
    const unsigned short* __restrict__ A,   // [M][K] bf16
    const unsigned short* __restrict__ BT,  // [N][K] bf16
    void* __restrict__ Cp,
    const int* __restrict__ row_map,
    int N, int K)
{
    __shared__ __align__(16) unsigned short As[TM * BK];
    __shared__ __align__(16) unsigned short Bs[TN * BK];

    const int m0   = blockIdx.x * TM;
    const int n0   = blockIdx.y * TN;
    const int tid  = threadIdx.x;
    const int lane = tid & 63;
    const int wv   = tid >> 6;
    const int wm   = (wv >> 1) * 64;
    const int wn   = (wv & 1) * 64;
    const int lrow = lane & 15;
    const int quad = lane >> 4;

    int gr[4], nr[4], csw[4];
#pragma unroll
    for (int c = 0; c < 4; c++) {
        int ch = (wv * 4 + c) * 64 + lane;
        int r  = ch >> 3;                          // 0..127
        csw[c] = ((ch & 7) ^ (r & 7)) << 3;
        gr[c]  = GATHER ? row_map[m0 + r] : (m0 + r);
        nr[c]  = n0 + r;
    }

    int aoff[4], asw[4], boff[4], bsw[4];
#pragma unroll
    for (int t = 0; t < 4; t++) {
        int ra = wm + t * 16 + lrow;
        aoff[t] = ra << 7;  asw[t] = (ra & 7) << 4;
        int rb = wn + t * 16 + lrow;
        boff[t] = rb << 7;  bsw[t] = (rb & 7) << 4;
    }

    f32x4 acc[4][4];
#pragma unroll
    for (int i = 0; i < 4; i++)
#pragma unroll
        for (int j = 0; j < 4; j++)
            acc[i][j] = (f32x4){0.f, 0.f, 0.f, 0.f};

    for (int kt = 0; kt < K; kt += BK) {
#pragma unroll
        for (int c = 0; c < 4; c++)
            gload_lds16(A + (size_t)gr[c] * K + kt + csw[c],
                        As + (wv * 4 + c) * 512);
#pragma unroll
        for (int c = 0; c < 4; c++)
            gload_lds16(BT + (size_t)nr[c] * K + kt + csw[c],
                        Bs + (wv * 4 + c) * 512);
        __syncthreads();

#pragma unroll
        for (int ks = 0; ks < BK; ks += 32) {
            const int cb = (ks << 1) + (quad << 4);
            bf16x8 af[4], bfr[4];
#pragma unroll
            for (int mt = 0; mt < 4; mt++)
                af[mt] = *(const bf16x8*)((const char*)As +
                                          aoff[mt] + (cb ^ asw[mt]));
#pragma unroll
            for (int nt = 0; nt < 4; nt++)
                bfr[nt] = *(const bf16x8*)((const char*)Bs +
                                           boff[nt] + (cb ^ bsw[nt]));
#pragma unroll
            for (int mt = 0; mt < 4; mt++)
#pragma unroll
                for (int nt = 0; nt < 4; nt++)
                    acc[mt][nt] = __builtin_amdgcn_mfma_f32_16x16x32_bf16(
                        af[mt], bfr[nt], acc[mt][nt], 0, 0, 0);
        }
        __syncthreads();
    }

#pragma unroll
    for (int nt = 0; nt < 4; nt++) {
        const int cb = n0 + wn + nt * 16;
        unsigned short* pp = nullptr;
        if (OUTMODE == 2) {
            int which = cb / C_DIM;
            int hc    = cb - which * C_DIM;
            int h     = hc / D_DIM;
            int d0    = hc - h * D_DIM;
            pp = (unsigned short*)Cp + (size_t)which * PLANE_ELEMS
               + (size_t)h * S_TOK * D_DIM + d0 + lrow;
        }
#pragma unroll
        for (int mt = 0; mt < 4; mt++)
#pragma unroll
            for (int r = 0; r < 4; r++) {
                int row = m0 + wm + mt * 16 + quad * 4 + r;
                if (OUTMODE == 0)
                    ((float*)Cp)[(size_t)row * N + cb + lrow] = acc[mt][nt][r];
                else
                    pp[(size_t)row * D_DIM] = f2bf(acc[mt][nt][r]);
            }
    }
}

// ---------------------------------------------------------------------------
// Fused RoPE + block attention v2 (unchanged from R4/R5 — ~50 us).
// ---------------------------------------------------------------------------
__global__ __launch_bounds__(256) void attn_v2(
    const unsigned short* __restrict__ planes,  // [3][H][S][D] bf16
    const float* __restrict__ cosp,
    const float* __restrict__ sinp,
    const int* __restrict__ wi,
    unsigned short* __restrict__ yw)            // [S][1280] bf16, WINDOWED
{
    __shared__ __align__(16) unsigned short Q_lds[4][16][88];
    __shared__ __align__(16) unsigned short K_lds[4][16][88];
    __shared__ __align__(16) unsigned short V_lds[4][1536];

    const int wave = threadIdx.x >> 6;
    const int lane = threadIdx.x & 63;
    const int b    = blockIdx.y;
    const int h    = blockIdx.x * 4 + wave;
    const int j16  = lane & 15;
    const int quad = lane >> 4;

    const unsigned short* Vsrc = planes + 2 * PLANE_ELEMS
        + ((size_t)h * S_TOK + b * BLK) * D_DIM;
    unsigned short* Vsl = &V_lds[wave][0];
#pragma unroll
    for (int c = 0; c < 3; c++)
        gload_lds16(Vsrc + c * 512 + lane * 8, Vsl + c * 512);

    const unsigned short* Qbase = planes + ((size_t)h * S_TOK + b * BLK) * D_DIM;
#pragma unroll
    for (int c = 0; c < 3; c++) {
        int ch = c * 64 + lane;
        if (ch < 160) {
            int r  = ch / 10;
            int d8 = (ch - r * 10) * 8;
            int crow = wi[b * BLK + r];
            const unsigned short* Qp = Qbase + (size_t)r * D_DIM + d8;
            u16x8 qv = *(const u16x8*)Qp;
            u16x8 kv = *(const u16x8*)(Qp + PLANE_ELEMS);
            const float* cp = cosp + (size_t)crow * D_DIM + d8;
            const float* sp = sinp + (size_t)crow * D_DIM + d8;
            f32x4 c0 = *(const f32x4*)cp, c1 = *(const f32x4*)(cp + 4);
            f32x4 s0 = *(const f32x4*)sp, s1 = *(const f32x4*)(sp + 4);
            u16x8 qo, ko;
#pragma unroll
            for (int j = 0; j < 8; j++) {
                float cw = (j < 4) ? c0[j] : c1[j - 4];
                float sw = (j < 4) ? s0[j] : s1[j - 4];
                float q = bf2f(qv[j]), k = bf2f(kv[j]);
                qo[j] = f2bf(q * cw + k * sw);
                ko[j] = f2bf(k * cw - q * sw);
            }
            *(u16x8*)&Q_lds[wave][r][d8] = qo;
            *(u16x8*)&K_lds[wave][r][d8] = ko;
        }
    }

    asm volatile("s_waitcnt vmcnt(0)" ::: "memory");
    __builtin_amdgcn_sched_barrier(0);

    const u16x8 zz = {0, 0, 0, 0, 0, 0, 0, 0};
    bf16x8 qf[3], kf[3];
#pragma unroll
    for (int s = 0; s < 3; s++) {
        int dcol = 32 * s + quad * 8;
        bool pad = (dcol >= D_DIM);
        int dc = pad ? 0 : dcol;
        u16x8 qv = *(const u16x8*)&Q_lds[wave][j16][dc];
        u16x8 kv = *(const u16x8*)&K_lds[wave][j16][dc];
        if (pad) { qv = zz; kv = zz; }
        qf[s] = __builtin_bit_cast(bf16x8, qv);
        kf[s] = __builtin_bit_cast(bf16x8, kv);
    }

    f32x4 sacc = (f32x4){0.f, 0.f, 0.f, 0.f};
#pragma unroll
    for (int s = 0; s < 3; s++)
        sacc = __builtin_amdgcn_mfma_f32_16x16x32_bf16(kf[s], qf[s], sacc, 0, 0, 0);

    const float scale = 0.11180339887498948f;   // 1/sqrt(80)
    float sc[4];
#pragma unroll
    for (int r = 0; r < 4; r++) sc[r] = sacc[r] * scale;
    float m = fmaxf(fmaxf(sc[0], sc[1]), fmaxf(sc[2], sc[3]));
    m = fmaxf(m, __shfl_xor(m, 16));
    m = fmaxf(m, __shfl_xor(m, 32));
    float e[4], sum = 0.f;
#pragma unroll
    for (int r = 0; r < 4; r++) { e[r] = __expf(sc[r] - m); sum += e[r]; }
    sum += __shfl_xor(sum, 16);
    sum += __shfl_xor(sum, 32);
    float inv = 1.f / sum;

    int sl = quad * 32 + j16;
    float pv0[4], pv1[4];
#pragma unroll
    for (int r = 0; r < 4; r++) pv0[r] = __shfl(e[r], sl & 63);
#pragma unroll
    for (int r = 0; r < 4; r++) pv1[r] = __shfl(e[r], (sl + 16) & 63);
    u16x8 pf;
#pragma unroll
    for (int r = 0; r < 4; r++) {
        pf[r]     = (quad < 2) ? f2bf(pv0[r]) : (unsigned short)0;
        pf[r + 4] = (quad < 2) ? f2bf(pv1[r]) : (unsigned short)0;
    }
    bf16x8 pfrag = __builtin_bit_cast(bf16x8, pf);

    u16x8 vf[5];
#pragma unroll
    for (int t = 0; t < 5; t++) {
#pragma unroll
        for (int e8 = 0; e8 < 8; e8++) {
            int kks = quad * 8 + e8;
            if (kks >= BLK) kks = e8;
            vf[t][e8] = Vsl[kks * D_DIM + t * 16 + j16];
        }
    }

    unsigned short* yrow = yw + (size_t)(b * BLK + j16) * C_DIM
                         + h * D_DIM + quad * 4;
#pragma unroll
    for (int t = 0; t < 5; t++) {
        f32x4 o = __builtin_amdgcn_mfma_f32_16x16x32_bf16(
            __builtin_bit_cast(bf16x8, vf[t]), pfrag,
            (f32x4){0.f, 0.f, 0.f, 0.f}, 0, 0, 0);
        u16x4 ov;
#pragma unroll
        for (int r = 0; r < 4; r++) ov[r] = f2bf(o[r] * inv);
        *(u16x4*)(yrow + t * 16) = ov;
    }
}

extern "C" void kernel_launch(void* const* d_in, const int* in_sizes, int n_in,
                              void* d_out, int out_size, void* d_ws, size_t ws_size,
                              hipStream_t stream)
{
    const float* x     = (const float*)d_in[0];
    const float* cosp  = (const float*)d_in[1];
    const float* sinp  = (const float*)d_in[2];
    const float* Wqkv  = (const float*)d_in[3];
    const float* Wproj = (const float*)d_in[4];
    const int*   wi    = (const int*)d_in[5];

    // workspace layout (bytes):
    //   qkv planes @ 0        : S*3840*2    = 125,829,120  ([3][H][S][D])
    //   yw     @ 125829120    : S*1280*2    =  41,943,040  (windowed order)
    //   wqkvT  @ 167772160    : 3840*1280*2 =   9,830,400   (bf16 [N][K])
    //   wprojT @ 177602560    : 1280*1280*2 =   3,276,800   (bf16 [N][K])
    //   xg     @ 180879360    : S*1280*2    =  41,943,040   (bf16 gathered x)
    //   inv    @ 180879360    : S*4 — ALIASES xg; written after GEMM1.
    char* ws = (char*)d_ws;
    unsigned short* planes = (unsigned short*)ws;
    unsigned short* yw     = (unsigned short*)(ws + 125829120ull);
    unsigned short* wqkvT  = (unsigned short*)(ws + 167772160ull);
    unsigned short* wprojT = (unsigned short*)(ws + 177602560ull);
    unsigned short* xg     = (unsigned short*)(ws + 180879360ull);
    int*            inv    = (int*)(ws + 180879360ull);

    // 0) weight prep: fp32 [K][N] -> bf16 [N][K]
    transpose_cvt<<<dim3(C3_DIM / 32, C_DIM / 32), 256, 0, stream>>>(
        Wqkv, wqkvT, C_DIM, C3_DIM);
    transpose_cvt<<<dim3(C_DIM / 32, C_DIM / 32), 256, 0, stream>>>(
        Wproj, wprojT, C_DIM, C_DIM);

    // 0b) gather + cvt prepass: xg[s] = bf16(x[wi[s]])
    gather_cvt<<<S_TOK * 160 / 256, 256, 0, stream>>>(x, wi, xg);

    // 1) qkv = xg @ W_qkv, written as [3][H][S][D] planes (rope fused in attn)
    gemm256<2, false><<<dim3(S_TOK / 256, C3_DIM / 256), 512, 0, stream>>>(
        xg, wqkvT, planes, nullptr, C3_DIM, C_DIM);

    // 1b) inverse permutation (xg dead; reuse its space)
    inv_perm<<<S_TOK / 256, 256, 0, stream>>>(wi, inv);

    // 2) fused rope + block attention; output WINDOWED (contiguous)
    attn_v2<<<dim3(H_DIM / 4, S_TOK / BLK), 256, 0, stream>>>(
        planes, cosp, sinp, wi, yw);

    // 3) out[r'] = yw[inv[r']] @ W_proj -> fp32 d_out (128^2 proven kernel)
    gemm_mfma<0, true><<<dim3(S_TOK / TM, C_DIM / TN), 256, 0, stream>>>(
        yw, wprojT, d_out, inv, C_DIM, C_DIM);
}